// Round 5
// baseline (180.875 us; speedup 1.0000x reference)
//
#include <hip/hip_runtime.h>
#include <cstdint>

// Fused butterfly-GLU-butterfly, round 8.
// Round-7 post-mortem: FAILED (absmax 47.8). Only numerics-affecting diff vs
// verified r6 was pk2 -> inline-asm v_cvt_pk_bf16_f32 (unverified operand->half
// order; guide m240 also flags hand-written cvt_pk as a loss). This round
// reverts pk2 to the verified +0x8000 + v_perm pack (bit-exact vs r0-r6) and
// keeps r7's structural diet, so it cleanly isolates the cvt_pk as the bug:
//   1. h as a runtime loop (#pragma unroll 1): main-loop text ~halves, fits I$.
//   2. setprio dropped (lockstep, m190-null); mats prefetch dropped (r6-null).
//   3. single-pass epilogue (all 32 rows fp32 = 128KB staged at once).

typedef float          v4f __attribute__((ext_vector_type(4)));
typedef unsigned int   u4i __attribute__((ext_vector_type(4)));
typedef unsigned int   u2i __attribute__((ext_vector_type(2)));
typedef short          bf8 __attribute__((ext_vector_type(8)));  // 8 x bf16

#define MFMA16(A, B, C) __builtin_amdgcn_mfma_f32_16x16x32_bf16(A, B, C, 0, 0, 0)

// Raw workgroup barrier: guarantees LDS visibility (lgkmcnt(0)) but leaves
// global loads in flight. Safe: no mid-kernel global communication.
#define BAR() do {                                          \
    asm volatile("s_waitcnt lgkmcnt(0)" ::: "memory");      \
    __builtin_amdgcn_s_barrier();                           \
    asm volatile("" ::: "memory");                          \
} while (0)

// pack two fp32 -> bf16x2 (a -> low16, b -> high16), round-to-nearest(ties away)
// VERIFIED implementation (rounds 0-6, absmax 0.125). Do not replace with
// v_cvt_pk_bf16_f32: r7 failed (absmax 47.8) with the inline-asm variant.
__device__ __forceinline__ unsigned pk2(float a, float b) {
    unsigned ua = __float_as_uint(a) + 0x8000u;
    unsigned ub = __float_as_uint(b) + 0x8000u;
    return __builtin_amdgcn_perm(ub, ua, 0x07060302u);  // {b.hi16, a.hi16}
}

__device__ __forceinline__ v4f ub4(u2i u) {   // unpack 4 bf16 -> v4f
    v4f r;
    r.x = __uint_as_float(u.x << 16); r.y = __uint_as_float(u.x & 0xffff0000u);
    r.z = __uint_as_float(u.y << 16); r.w = __uint_as_float(u.y & 0xffff0000u);
    return r;
}

__device__ __forceinline__ float sigmf(float g) {
    return __builtin_amdgcn_rcpf(1.0f + __expf(-g));
}
__device__ __forceinline__ v4f sig4(v4f g) {
    v4f r; r.x = sigmf(g.x); r.y = sigmf(g.y); r.z = sigmf(g.z); r.w = sigmf(g.w);
    return r;
}

// byte offset into a [32 rows][1024 halfword] bf16 LDS tile, bank-swizzled
__device__ __forceinline__ int ab(int row, int hw) {
    return (row << 11) + (((hw) << 1) ^ ((row & 7) << 4));
}

// ---------------------------------------------------------------------------
// Pre-pass: 384 combined 32x32 bf16 matrices into d_ws (A-fragment order).
//   mid   0..127 : L1A [s][g]  stages 0..4 , p = 32g + r        (tw1)
//   mid 128..255 : L1B [s][l]  stages 5..9 , p = l + 32r        (tw1)
//   mid 256..319 : L2A [g2]    stages 0..4 , p = 32g2 + r       (tw2)
//   mid 320..383 : L2B [b][l2] stages 5..9 , p = l2+32r+1024b   (tw2),
//                  rows scaled by tw2[stage10][l2+32r][0][b]
// ---------------------------------------------------------------------------
struct MP { const float* twf; int np, rbase, rstep, j0; };
__device__ __forceinline__ MP mparams(int mid, const float* tw1, const float* tw2) {
    MP p;
    if (mid < 128)      { p.twf = tw1 + (mid >> 5) * 20480;         p.np = 512;  p.rbase = (mid & 31) * 32; p.rstep = 1;  p.j0 = 0; }
    else if (mid < 256) { p.twf = tw1 + ((mid - 128) >> 5) * 20480; p.np = 512;  p.rbase = mid & 31;        p.rstep = 32; p.j0 = 5; }
    else if (mid < 320) { p.twf = tw2; p.np = 1024; p.rbase = (mid - 256) * 32; p.rstep = 1;  p.j0 = 0; }
    else                { p.twf = tw2; p.np = 1024;
                          p.rbase = (mid & 31) + (((mid - 320) >> 5) << 10);    p.rstep = 32; p.j0 = 5; }
    return p;
}

__global__ void build_mats(const float* __restrict__ tw1,
                           const float* __restrict__ tw2,
                           unsigned short* __restrict__ wsm)
{
    __shared__ v4f            tlds[160];   // 2 mids x 5 stages x 16 pairs
    __shared__ float          slds[64];    // 2 mids x 32 stage-10 row scales
    __shared__ unsigned short obuf[2048];  // 4KB output staging
    const int t = threadIdx.x;
    const int midb = blockIdx.x * 2;

    #pragma unroll
    for (int qq = 0; qq < 3; ++qq) {
        const int q = t + qq * 64;
        if (q < 160) {
            const int ml = (q >= 80) ? 1 : 0, rem = q - ml * 80;
            const int jj = rem >> 4, pr = rem & 15;
            const MP p = mparams(midb + ml, tw1, tw2);
            const int j  = p.j0 + jj;
            const int r0 = ((pr >> jj) << (jj + 1)) | (pr & ((1 << jj) - 1));
            const int pp = p.rbase + r0 * p.rstep;
            const int tidx = ((pp >> (j + 1)) << j) | (pp & ((1 << j) - 1));
            tlds[q] = *(const v4f*)(p.twf + (size_t)(j * p.np + tidx) * 4);
        }
    }
    {
        const int ml2 = t >> 5, r = t & 31, mid = midb + ml2;
        if (mid >= 320) {
            const int l2s = mid & 31, sb = (mid - 320) >> 5;
            slds[t] = tw2[(size_t)(10 * 1024 + l2s + 32 * r) * 4 + sb];
        }
    }
    __syncthreads();

    const int ml = t >> 5, c = t & 31, mid = midb + ml;
    float v[32];
    #pragma unroll
    for (int r = 0; r < 32; ++r) v[r] = (r == c) ? 1.0f : 0.0f;

    #pragma unroll
    for (int jj = 0; jj < 5; ++jj) {
        #pragma unroll
        for (int pr = 0; pr < 16; ++pr) {
            const int r0 = ((pr >> jj) << (jj + 1)) | (pr & ((1 << jj) - 1));
            const int r1 = r0 | (1 << jj);
            const v4f T  = tlds[ml * 80 + jj * 16 + pr];
            const float a = v[r0], b = v[r1];
            v[r0] = T.x * a + T.y * b;
            v[r1] = T.z * a + T.w * b;
        }
    }
    if (mid >= 320) {
        #pragma unroll
        for (int r = 0; r < 32; ++r) v[r] *= slds[ml * 32 + r];
    }
    #pragma unroll
    for (int r = 0; r < 32; ++r) {
        const int mt   = r >> 4;
        const int lane = (r & 15) + ((c >> 3) << 4);
        obuf[((ml * 2 + mt) * 64 + lane) * 8 + (c & 7)] =
            (unsigned short)((__float_as_uint(v[r]) + 0x8000u) >> 16);
    }
    __syncthreads();
    {
        const u4i* ob = (const u4i*)obuf;                 // 256 x 16B
        u4i* gb = (u4i*)(wsm + (size_t)midb * 1024);
        #pragma unroll
        for (int k = 0; k < 4; ++k) gb[t * 4 + k] = ob[t * 4 + k];
    }
}

// ---------------------------------------------------------------------------
// Main fused kernel. 512 blocks x 32 rows x 512 thr.
// LDS 136KB = actA(64K) + actB(64K) + b1t16(8K); 1 block/CU, 8 waves.
// Transposed-tile convention: value at position p stored at hw = 32*(p&31)+(p>>5).
// ---------------------------------------------------------------------------
__global__ __launch_bounds__(512, 2) void glu_bfly(
    const float* __restrict__ x, const float* __restrict__ b1,
    const float* __restrict__ b2, const bf8* __restrict__ mats,
    float* __restrict__ out)
{
    extern __shared__ char lds[];                 // 139264 B
    char*           actA  = lds;
    char*           actB  = lds + 65536;
    unsigned short* b1t16 = (unsigned short*)(lds + 131072);

    const int t = threadIdx.x, w = t >> 6, l = t & 63, lr = l & 15, lk = l >> 4;
    const int row0 = blockIdx.x * 32;
    const v4f vz = {0.f, 0.f, 0.f, 0.f};
    const bf8* mp = mats + l;   // per-lane base; frag index = (mid*2+mt)*64

    // ---- stage b1 (bf16) -> b1t16[(s<<10)+((r&31)<<5)+(r>>5)] -------------------
    {
        const v4f* bp = (const v4f*)(b1 + t * 8);
        const v4f a = bp[0], b = bp[1];
        const float vals[8] = {a.x, a.y, a.z, a.w, b.x, b.y, b.z, b.w};
        #pragma unroll
        for (int k = 0; k < 8; ++k) {
            const int gid = t * 8 + k, s = gid >> 10, r = gid & 1023;
            b1t16[(s << 10) + ((r & 31) << 5) + (r >> 5)] =
                (unsigned short)((__float_as_uint(vals[k]) + 0x8000u) >> 16);
        }
    }

    // ---- x B-fragments (32 rows via nh), reused by all four L1A applications ----
    bf8 xf[4][2];
    #pragma unroll
    for (int gi = 0; gi < 4; ++gi)
    #pragma unroll
    for (int nh = 0; nh < 2; ++nh) {
        const float* xp = x + (size_t)(row0 + nh * 16 + lr) * 1024 + (w * 4 + gi) * 32 + lk * 8;
        const v4f a = *(const v4f*)xp, b = *(const v4f*)(xp + 4);
        u4i uu; uu.x = pk2(a.x, a.y); uu.y = pk2(a.z, a.w);
        uu.z = pk2(b.x, b.y); uu.w = pk2(b.z, b.w);
        xf[gi][nh] = __builtin_bit_cast(bf8, uu);
    }

    unsigned z0p[4][2][2][2];   // half-0 L2B result, bf16-packed
    v4f fin[4][2][2];           // z0 + z1 (pre-bias)

    #pragma unroll 1
    for (int h = 0; h < 2; ++h) {

        // ---- PH1 (merged): L1A stack h -> actA, stack h+2 -> actB (transposed) --
        #pragma unroll
        for (int pass = 0; pass < 2; ++pass) {
            const int s = h + pass * 2;
            char* dst = pass ? actB : actA;
            v4f acc[4][2][2];
            #pragma unroll
            for (int gi = 0; gi < 4; ++gi) {
                const bf8 a0 = mp[((s * 32 + w * 4 + gi) * 2 + 0) * 64];
                const bf8 a1 = mp[((s * 32 + w * 4 + gi) * 2 + 1) * 64];
                #pragma unroll
                for (int nh = 0; nh < 2; ++nh) {
                    acc[gi][nh][0] = MFMA16(a0, xf[gi][nh], vz);
                    acc[gi][nh][1] = MFMA16(a1, xf[gi][nh], vz);
                }
            }
            #pragma unroll
            for (int nh = 0; nh < 2; ++nh)
            #pragma unroll
            for (int mt = 0; mt < 2; ++mt)
            #pragma unroll
            for (int rg = 0; rg < 4; ++rg) {
                const int m = mt * 16 + lk * 4 + rg;
                u2i pv;
                pv.x = pk2(acc[0][nh][mt][rg], acc[1][nh][mt][rg]);
                pv.y = pk2(acc[2][nh][mt][rg], acc[3][nh][mt][rg]);
                *(u2i*)(dst + ab(nh * 16 + lr, 32 * m + 4 * w)) = pv;
            }
        }
        BAR();

        // ---- PH2: L1B(a) + L1B(g) + bias + GLU -> uacc (regs) -------------------
        v4f uacc[4][2][2];
        #pragma unroll
        for (int li = 0; li < 4; ++li) {
            const int lg = w * 4 + li;
            const bf8 fa0 = *(const bf8*)(actA + ab(lr,      32 * lg + 8 * lk));
            const bf8 fa1 = *(const bf8*)(actA + ab(16 + lr, 32 * lg + 8 * lk));
            const bf8 fg0 = *(const bf8*)(actB + ab(lr,      32 * lg + 8 * lk));
            const bf8 fg1 = *(const bf8*)(actB + ab(16 + lr, 32 * lg + 8 * lk));
            const int mida = 128 + h * 32 + lg, midg = 128 + (h + 2) * 32 + lg;
            const bf8 aa0 = mp[(mida * 2 + 0) * 64];
            const bf8 aa1 = mp[(mida * 2 + 1) * 64];
            const bf8 ag0 = mp[(midg * 2 + 0) * 64];
            const bf8 ag1 = mp[(midg * 2 + 1) * 64];
            v4f ha[2][2], hg[2][2];
            ha[0][0] = MFMA16(aa0, fa0, vz); ha[0][1] = MFMA16(aa1, fa0, vz);
            ha[1][0] = MFMA16(aa0, fa1, vz); ha[1][1] = MFMA16(aa1, fa1, vz);
            hg[0][0] = MFMA16(ag0, fg0, vz); hg[0][1] = MFMA16(ag1, fg0, vz);
            hg[1][0] = MFMA16(ag0, fg1, vz); hg[1][1] = MFMA16(ag1, fg1, vz);
            const int bia = ((h * 32 + lg) << 5) + lk * 4;
            const int big = (((h + 2) * 32 + lg) << 5) + lk * 4;
            const v4f ba0 = ub4(*(const u2i*)&b1t16[bia]);
            const v4f ba1 = ub4(*(const u2i*)&b1t16[bia + 16]);
            const v4f bg0 = ub4(*(const u2i*)&b1t16[big]);
            const v4f bg1 = ub4(*(const u2i*)&b1t16[big + 16]);
            #pragma unroll
            for (int nh = 0; nh < 2; ++nh) {
                uacc[li][nh][0] = (ha[nh][0] + ba0) * sig4(hg[nh][0] + bg0);
                uacc[li][nh][1] = (ha[nh][1] + ba1) * sig4(hg[nh][1] + bg1);
            }
        }
        BAR();   // all reads of actA/actB complete
        #pragma unroll
        for (int nh = 0; nh < 2; ++nh)
        #pragma unroll
        for (int mt = 0; mt < 2; ++mt)
        #pragma unroll
        for (int rg = 0; rg < 4; ++rg) {
            const int m = mt * 16 + lk * 4 + rg;
            u2i pv;
            pv.x = pk2(uacc[0][nh][mt][rg], uacc[1][nh][mt][rg]);
            pv.y = pk2(uacc[2][nh][mt][rg], uacc[3][nh][mt][rg]);
            *(u2i*)(actA + ab(nh * 16 + lr, 32 * m + 4 * w)) = pv;  // plain: hw = p
        }
        BAR();

        // ---- PH3: L2A: u (actA, plain) -> zA (actB, transposed) -----------------
        {
            v4f acc[4][2][2];
            #pragma unroll
            for (int gi = 0; gi < 4; ++gi) {
                const int g = w * 4 + gi, mid = 256 + 32 * h + g;
                const bf8 a0 = mp[(mid * 2 + 0) * 64];
                const bf8 a1 = mp[(mid * 2 + 1) * 64];
                #pragma unroll
                for (int nh = 0; nh < 2; ++nh) {
                    const bf8 f = *(const bf8*)(actA + ab(nh * 16 + lr, 32 * g + 8 * lk));
                    acc[gi][nh][0] = MFMA16(a0, f, vz);
                    acc[gi][nh][1] = MFMA16(a1, f, vz);
                }
            }
            #pragma unroll
            for (int nh = 0; nh < 2; ++nh)
            #pragma unroll
            for (int mt = 0; mt < 2; ++mt)
            #pragma unroll
            for (int rg = 0; rg < 4; ++rg) {
                const int m = mt * 16 + lk * 4 + rg;
                u2i pv;
                pv.x = pk2(acc[0][nh][mt][rg], acc[1][nh][mt][rg]);
                pv.y = pk2(acc[2][nh][mt][rg], acc[3][nh][mt][rg]);
                *(u2i*)(actB + ab(nh * 16 + lr, 32 * m + 4 * w)) = pv;
            }
        }
        BAR();

        // ---- PH4: L2B (stage-10 twiddles pre-folded): result stays in regs ------
        #pragma unroll
        for (int li = 0; li < 4; ++li) {
            const int lg = w * 4 + li, mid = 320 + 32 * h + lg;
            const bf8 f0 = *(const bf8*)(actB + ab(lr,      32 * lg + 8 * lk));
            const bf8 f1 = *(const bf8*)(actB + ab(16 + lr, 32 * lg + 8 * lk));
            const bf8 a0 = mp[(mid * 2 + 0) * 64];
            const bf8 a1 = mp[(mid * 2 + 1) * 64];
            v4f zz[2][2];
            zz[0][0] = MFMA16(a0, f0, vz); zz[0][1] = MFMA16(a1, f0, vz);
            zz[1][0] = MFMA16(a0, f1, vz); zz[1][1] = MFMA16(a1, f1, vz);
            if (h == 0) {
                #pragma unroll
                for (int nh = 0; nh < 2; ++nh)
                #pragma unroll
                for (int mt = 0; mt < 2; ++mt) {
                    z0p[li][nh][mt][0] = pk2(zz[nh][mt].x, zz[nh][mt].y);
                    z0p[li][nh][mt][1] = pk2(zz[nh][mt].z, zz[nh][mt].w);
                }
            } else {
                #pragma unroll
                for (int nh = 0; nh < 2; ++nh)
                #pragma unroll
                for (int mt = 0; mt < 2; ++mt) {
                    u2i uu; uu.x = z0p[li][nh][mt][0]; uu.y = z0p[li][nh][mt][1];
                    fin[li][nh][mt] = zz[nh][mt] + ub4(uu);
                }
            }
        }
        BAR();   // protects actA/actB WAR vs next-h PH1 (and epilogue staging)
    } // h

    // ---- epilogue: stage all 32 rows fp32 (128KB) then coalesced store ----------
    #pragma unroll
    for (int nh = 0; nh < 2; ++nh)
    #pragma unroll
    for (int mt = 0; mt < 2; ++mt)
    #pragma unroll
    for (int rg = 0; rg < 4; ++rg) {
        const int p0 = 4 * w + 32 * (mt * 16 + lk * 4 + rg);
        v4f vv;
        vv.x = fin[0][nh][mt][rg]; vv.y = fin[1][nh][mt][rg];
        vv.z = fin[2][nh][mt][rg]; vv.w = fin[3][nh][mt][rg];
        *(v4f*)(lds + ((nh * 16 + lr) << 12) + ((p0 << 2) ^ ((lr & 7) << 4))) = vv;
    }
    BAR();
    {
        const int row = t >> 5, c0 = (t & 31) * 4;
        #pragma unroll
        for (int nh = 0; nh < 2; ++nh)
        #pragma unroll
        for (int i = 0; i < 8; ++i) {
            const int col = c0 + 128 * i;
            v4f ov = *(const v4f*)(lds + ((nh * 16 + row) << 12) +
                                   ((col << 2) ^ ((row & 7) << 4)));
            ov += *(const v4f*)(b2 + col);
            *(v4f*)(out + (size_t)(row0 + nh * 16 + row) * 1024 + col) = ov;
        }
    }
}

extern "C" void kernel_launch(void* const* d_in, const int* in_sizes, int n_in,
                              void* d_out, int out_size, void* d_ws, size_t ws_size,
                              hipStream_t stream) {
    const float* x   = (const float*)d_in[0];
    const float* tw1 = (const float*)d_in[1];
    const float* b1  = (const float*)d_in[2];
    const float* tw2 = (const float*)d_in[3];
    const float* b2  = (const float*)d_in[4];

    build_mats<<<192, 64, 0, stream>>>(tw1, tw2, (unsigned short*)d_ws);

    (void)hipFuncSetAttribute((const void*)glu_bfly,
                              hipFuncAttributeMaxDynamicSharedMemorySize, 139264);
    glu_bfly<<<512, 512, 139264, stream>>>(x, b1, b2, (const bf8*)d_ws,
                                           (float*)d_out);
}

// Round 6
// 166.531 us; speedup vs baseline: 1.0861x; 1.0861x over previous
//
#include <hip/hip_runtime.h>
#include <cstdint>

// Fused butterfly-GLU-butterfly, round 9.
// Round-8 post-mortem: runtime-h loop caused scratch spills (WRITE_SIZE 65->100MB)
// -> 106us. cvt_pk confirmed as the r7 bug; verified v_perm pack restored.
// Standing: ~65us floor, insensitive to waves (r5 vs r6) and mats prefetch (r6);
// VALU 26% / LDS ~18% / MFMA 8% -- nothing saturated. Remaining theory:
// barrier-lockstep phase serialization (all waves in the same phase; dependent
// ds_read->MFMA->pk2->ds_write chain exposed every phase). Fix: the h=0 / h=1
// streams are independent until the final z0+z1 -- pipeline them skewed by one
// phase in one block. R=16 rows, four 32KB act tiles (A0,B0,A1,B1) + b1 = 136KB,
// 7 barriers per block (was 12), every segment pairs one stream's MFMA cluster
// with the other stream's VALU/LDS phase. Phase bodies verbatim from verified
// r5 (identical arithmetic order -> absmax must stay 0.125). Spill canary:
// WRITE_SIZE must be 65536.

typedef float          v4f __attribute__((ext_vector_type(4)));
typedef unsigned int   u4i __attribute__((ext_vector_type(4)));
typedef unsigned int   u2i __attribute__((ext_vector_type(2)));
typedef short          bf8 __attribute__((ext_vector_type(8)));  // 8 x bf16

#define MFMA16(A, B, C) __builtin_amdgcn_mfma_f32_16x16x32_bf16(A, B, C, 0, 0, 0)

// Raw workgroup barrier: guarantees LDS visibility (lgkmcnt(0)) but leaves
// global loads in flight. Safe: no mid-kernel global communication.
#define BAR() do {                                          \
    asm volatile("s_waitcnt lgkmcnt(0)" ::: "memory");      \
    __builtin_amdgcn_s_barrier();                           \
    asm volatile("" ::: "memory");                          \
} while (0)

// pack two fp32 -> bf16x2 (a -> low16, b -> high16), round-to-nearest(ties away)
// VERIFIED (rounds 0-6,8; absmax 0.125). Do NOT swap for v_cvt_pk_bf16_f32
// inline asm: r7 failed with absmax 47.8.
__device__ __forceinline__ unsigned pk2(float a, float b) {
    unsigned ua = __float_as_uint(a) + 0x8000u;
    unsigned ub = __float_as_uint(b) + 0x8000u;
    return __builtin_amdgcn_perm(ub, ua, 0x07060302u);  // {b.hi16, a.hi16}
}

__device__ __forceinline__ v4f ub4(u2i u) {   // unpack 4 bf16 -> v4f
    v4f r;
    r.x = __uint_as_float(u.x << 16); r.y = __uint_as_float(u.x & 0xffff0000u);
    r.z = __uint_as_float(u.y << 16); r.w = __uint_as_float(u.y & 0xffff0000u);
    return r;
}

__device__ __forceinline__ float sigmf(float g) {
    return __builtin_amdgcn_rcpf(1.0f + __expf(-g));
}
__device__ __forceinline__ v4f sig4(v4f g) {
    v4f r; r.x = sigmf(g.x); r.y = sigmf(g.y); r.z = sigmf(g.z); r.w = sigmf(g.w);
    return r;
}

// byte offset into a [16 rows][1024 halfword] bf16 LDS tile, bank-swizzled
__device__ __forceinline__ int ab16(int row, int hw) {
    return (row << 11) + (((hw) << 1) ^ ((row & 7) << 4));
}

// ---------------------------------------------------------------------------
// Pre-pass: 384 combined 32x32 bf16 matrices into d_ws (A-fragment order).
//   mid   0..127 : L1A [s][g]  stages 0..4 , p = 32g + r        (tw1)
//   mid 128..255 : L1B [s][l]  stages 5..9 , p = l + 32r        (tw1)
//   mid 256..319 : L2A [g2]    stages 0..4 , p = 32g2 + r       (tw2)
//   mid 320..383 : L2B [b][l2] stages 5..9 , p = l2+32r+1024b   (tw2),
//                  rows scaled by tw2[stage10][l2+32r][0][b]
// ---------------------------------------------------------------------------
struct MP { const float* twf; int np, rbase, rstep, j0; };
__device__ __forceinline__ MP mparams(int mid, const float* tw1, const float* tw2) {
    MP p;
    if (mid < 128)      { p.twf = tw1 + (mid >> 5) * 20480;         p.np = 512;  p.rbase = (mid & 31) * 32; p.rstep = 1;  p.j0 = 0; }
    else if (mid < 256) { p.twf = tw1 + ((mid - 128) >> 5) * 20480; p.np = 512;  p.rbase = mid & 31;        p.rstep = 32; p.j0 = 5; }
    else if (mid < 320) { p.twf = tw2; p.np = 1024; p.rbase = (mid - 256) * 32; p.rstep = 1;  p.j0 = 0; }
    else                { p.twf = tw2; p.np = 1024;
                          p.rbase = (mid & 31) + (((mid - 320) >> 5) << 10);    p.rstep = 32; p.j0 = 5; }
    return p;
}

__global__ void build_mats(const float* __restrict__ tw1,
                           const float* __restrict__ tw2,
                           unsigned short* __restrict__ wsm)
{
    __shared__ v4f            tlds[160];   // 2 mids x 5 stages x 16 pairs
    __shared__ float          slds[64];    // 2 mids x 32 stage-10 row scales
    __shared__ unsigned short obuf[2048];  // 4KB output staging
    const int t = threadIdx.x;
    const int midb = blockIdx.x * 2;

    #pragma unroll
    for (int qq = 0; qq < 3; ++qq) {
        const int q = t + qq * 64;
        if (q < 160) {
            const int ml = (q >= 80) ? 1 : 0, rem = q - ml * 80;
            const int jj = rem >> 4, pr = rem & 15;
            const MP p = mparams(midb + ml, tw1, tw2);
            const int j  = p.j0 + jj;
            const int r0 = ((pr >> jj) << (jj + 1)) | (pr & ((1 << jj) - 1));
            const int pp = p.rbase + r0 * p.rstep;
            const int tidx = ((pp >> (j + 1)) << j) | (pp & ((1 << j) - 1));
            tlds[q] = *(const v4f*)(p.twf + (size_t)(j * p.np + tidx) * 4);
        }
    }
    {
        const int ml2 = t >> 5, r = t & 31, mid = midb + ml2;
        if (mid >= 320) {
            const int l2s = mid & 31, sb = (mid - 320) >> 5;
            slds[t] = tw2[(size_t)(10 * 1024 + l2s + 32 * r) * 4 + sb];
        }
    }
    __syncthreads();

    const int ml = t >> 5, c = t & 31, mid = midb + ml;
    float v[32];
    #pragma unroll
    for (int r = 0; r < 32; ++r) v[r] = (r == c) ? 1.0f : 0.0f;

    #pragma unroll
    for (int jj = 0; jj < 5; ++jj) {
        #pragma unroll
        for (int pr = 0; pr < 16; ++pr) {
            const int r0 = ((pr >> jj) << (jj + 1)) | (pr & ((1 << jj) - 1));
            const int r1 = r0 | (1 << jj);
            const v4f T  = tlds[ml * 80 + jj * 16 + pr];
            const float a = v[r0], b = v[r1];
            v[r0] = T.x * a + T.y * b;
            v[r1] = T.z * a + T.w * b;
        }
    }
    if (mid >= 320) {
        #pragma unroll
        for (int r = 0; r < 32; ++r) v[r] *= slds[ml * 32 + r];
    }
    #pragma unroll
    for (int r = 0; r < 32; ++r) {
        const int mt   = r >> 4;
        const int lane = (r & 15) + ((c >> 3) << 4);
        obuf[((ml * 2 + mt) * 64 + lane) * 8 + (c & 7)] =
            (unsigned short)((__float_as_uint(v[r]) + 0x8000u) >> 16);
    }
    __syncthreads();
    {
        const u4i* ob = (const u4i*)obuf;                 // 256 x 16B
        u4i* gb = (u4i*)(wsm + (size_t)midb * 1024);
        #pragma unroll
        for (int k = 0; k < 4; ++k) gb[t * 4 + k] = ob[t * 4 + k];
    }
}

// ---------------------------------------------------------------------------
// Main fused kernel. 1024 blocks x 16 rows x 512 thr.
// LDS 136KB = A0,B0,A1,B1 (4 x 32KB act tiles) + b1t16 (8KB). 1 block/CU.
// Two independent h-streams pipelined with skew 1 across 7 barriers.
// Transposed-tile convention: value at position p stored at hw = 32*(p&31)+(p>>5).
// ---------------------------------------------------------------------------
__global__ __launch_bounds__(512, 2) void glu_bfly(
    const float* __restrict__ x, const float* __restrict__ b1,
    const float* __restrict__ b2, const bf8* __restrict__ mats,
    float* __restrict__ out)
{
    extern __shared__ char lds[];                 // 139264 B
    char* A0 = lds;
    char* B0 = lds + 32768;
    char* A1 = lds + 65536;
    char* B1 = lds + 98304;
    unsigned short* b1t16 = (unsigned short*)(lds + 131072);

    const int t = threadIdx.x, w = t >> 6, l = t & 63, lr = l & 15, lk = l >> 4;
    const int row0 = blockIdx.x * 16;
    const v4f vz = {0.f, 0.f, 0.f, 0.f};
    const bf8* mp = mats + l;   // per-lane base; frag index = (mid*2+mt)*64

    // ---- stage b1 (bf16) -> b1t16[(s<<10)+((r&31)<<5)+(r>>5)] -------------------
    {
        const v4f* bp = (const v4f*)(b1 + t * 8);
        const v4f a = bp[0], b = bp[1];
        const float vals[8] = {a.x, a.y, a.z, a.w, b.x, b.y, b.z, b.w};
        #pragma unroll
        for (int k = 0; k < 8; ++k) {
            const int gid = t * 8 + k, s = gid >> 10, r = gid & 1023;
            b1t16[(s << 10) + ((r & 31) << 5) + (r >> 5)] =
                (unsigned short)((__float_as_uint(vals[k]) + 0x8000u) >> 16);
        }
    }

    // ---- x B-fragments, reused by all four S1 applications ----------------------
    bf8 xf[4];
    #pragma unroll
    for (int gi = 0; gi < 4; ++gi) {
        const float* xp = x + (size_t)(row0 + lr) * 1024 + (w * 4 + gi) * 32 + lk * 8;
        const v4f a = *(const v4f*)xp, b = *(const v4f*)(xp + 4);
        u4i uu; uu.x = pk2(a.x, a.y); uu.y = pk2(a.z, a.w);
        uu.z = pk2(b.x, b.y); uu.w = pk2(b.z, b.w);
        xf[gi] = __builtin_bit_cast(bf8, uu);
    }

    v4f uacc0[4][2], uacc1[4][2];
    unsigned z0p[4][2][2];   // stream-0 L2B result, bf16-packed
    v4f fin[4][2];           // z0 + z1 (pre-bias)

    // ---- phase bodies (verbatim r5 arithmetic) ----------------------------------
    auto S1 = [&](int s, char* dst) {        // L1A stack s -> dst (transposed)
        v4f acc[2][4];
        #pragma unroll
        for (int mt = 0; mt < 2; ++mt)
        #pragma unroll
        for (int gi = 0; gi < 4; ++gi) {
            const bf8 am = mp[((s * 32 + w * 4 + gi) * 2 + mt) * 64];
            acc[mt][gi] = MFMA16(am, xf[gi], vz);
        }
        #pragma unroll
        for (int mt = 0; mt < 2; ++mt)
        #pragma unroll
        for (int rg = 0; rg < 4; ++rg) {
            const int m = mt * 16 + lk * 4 + rg;
            u2i pv;
            pv.x = pk2(acc[mt][0][rg], acc[mt][1][rg]);
            pv.y = pk2(acc[mt][2][rg], acc[mt][3][rg]);
            *(u2i*)(dst + ab16(lr, 32 * m + 4 * w)) = pv;
        }
    };

    auto S2 = [&](int h, char* A, char* B, v4f (&uacc)[4][2]) {  // L1B+bias+GLU
        #pragma unroll
        for (int li = 0; li < 4; ++li) {
            const int lg = w * 4 + li;
            const bf8 fa = *(const bf8*)(A + ab16(lr, 32 * lg + 8 * lk));
            const bf8 fg = *(const bf8*)(B + ab16(lr, 32 * lg + 8 * lk));
            const int mida = 128 + h * 32 + lg, midg = 128 + (h + 2) * 32 + lg;
            const bf8 aa0 = mp[(mida * 2 + 0) * 64];
            const bf8 aa1 = mp[(mida * 2 + 1) * 64];
            const bf8 ag0 = mp[(midg * 2 + 0) * 64];
            const bf8 ag1 = mp[(midg * 2 + 1) * 64];
            const v4f ha0 = MFMA16(aa0, fa, vz), ha1 = MFMA16(aa1, fa, vz);
            const v4f hg0 = MFMA16(ag0, fg, vz), hg1 = MFMA16(ag1, fg, vz);
            const int bia = ((h * 32 + lg) << 5) + lk * 4;
            const int big = (((h + 2) * 32 + lg) << 5) + lk * 4;
            const v4f ba0 = ub4(*(const u2i*)&b1t16[bia]);
            const v4f ba1 = ub4(*(const u2i*)&b1t16[bia + 16]);
            const v4f bg0 = ub4(*(const u2i*)&b1t16[big]);
            const v4f bg1 = ub4(*(const u2i*)&b1t16[big + 16]);
            uacc[li][0] = (ha0 + ba0) * sig4(hg0 + bg0);
            uacc[li][1] = (ha1 + ba1) * sig4(hg1 + bg1);
        }
    };

    auto S3 = [&](char* A, const v4f (&uacc)[4][2]) {   // u -> A (plain: hw = p)
        #pragma unroll
        for (int mt = 0; mt < 2; ++mt)
        #pragma unroll
        for (int rg = 0; rg < 4; ++rg) {
            const int m = mt * 16 + lk * 4 + rg;
            u2i pv;
            pv.x = pk2(uacc[0][mt][rg], uacc[1][mt][rg]);
            pv.y = pk2(uacc[2][mt][rg], uacc[3][mt][rg]);
            *(u2i*)(A + ab16(lr, 32 * m + 4 * w)) = pv;
        }
    };

    auto S4 = [&](int h, char* A, char* B) {   // L2A: A (plain) -> B (transposed)
        v4f acc[2][4];
        #pragma unroll
        for (int gi = 0; gi < 4; ++gi) {
            const int g = w * 4 + gi, mid = 256 + 32 * h + g;
            const bf8 f  = *(const bf8*)(A + ab16(lr, 32 * g + 8 * lk));
            const bf8 a0 = mp[(mid * 2 + 0) * 64];
            const bf8 a1 = mp[(mid * 2 + 1) * 64];
            acc[0][gi] = MFMA16(a0, f, vz);
            acc[1][gi] = MFMA16(a1, f, vz);
        }
        #pragma unroll
        for (int mt = 0; mt < 2; ++mt)
        #pragma unroll
        for (int rg = 0; rg < 4; ++rg) {
            const int m = mt * 16 + lk * 4 + rg;
            u2i pv;
            pv.x = pk2(acc[mt][0][rg], acc[mt][1][rg]);
            pv.y = pk2(acc[mt][2][rg], acc[mt][3][rg]);
            *(u2i*)(B + ab16(lr, 32 * m + 4 * w)) = pv;
        }
    };

    // ---- pipelined schedule: stream0 = {stacks 0,2}, stream1 = {stacks 1,3} -----
    // seg0: S1(0)
    S1(0, A0); S1(2, B0);
    BAR();
    // seg1: S2(0) || S1(1)
    S2(0, A0, B0, uacc0);
    S1(1, A1); S1(3, B1);
    BAR();
    // seg2: S3(0) || S2(1)
    S3(A0, uacc0);
    S2(1, A1, B1, uacc1);
    BAR();
    // seg3: S4(0) || S3(1)
    S4(0, A0, B0);
    S3(A1, uacc1);
    BAR();
    // seg4: S5(0) || S4(1)
    #pragma unroll
    for (int li = 0; li < 4; ++li) {         // S5(0): L2B h=0 -> z0p (regs)
        const int lg = w * 4 + li, mid = 320 + 0 + lg;
        const bf8 f  = *(const bf8*)(B0 + ab16(lr, 32 * lg + 8 * lk));
        const bf8 a0 = mp[(mid * 2 + 0) * 64];
        const bf8 a1 = mp[(mid * 2 + 1) * 64];
        const v4f z0 = MFMA16(a0, f, vz);
        const v4f z1 = MFMA16(a1, f, vz);
        z0p[li][0][0] = pk2(z0.x, z0.y); z0p[li][0][1] = pk2(z0.z, z0.w);
        z0p[li][1][0] = pk2(z1.x, z1.y); z0p[li][1][1] = pk2(z1.z, z1.w);
    }
    S4(1, A1, B1);
    BAR();
    // seg5: S5(1) + fin staging (fp32, lds[0..64K) = A0+B0 region, dead now)
    #pragma unroll
    for (int li = 0; li < 4; ++li) {         // S5(1): L2B h=1, fin = z + z0
        const int lg = w * 4 + li, mid = 320 + 32 + lg;
        const bf8 f  = *(const bf8*)(B1 + ab16(lr, 32 * lg + 8 * lk));
        const bf8 a0 = mp[(mid * 2 + 0) * 64];
        const bf8 a1 = mp[(mid * 2 + 1) * 64];
        const v4f z0 = MFMA16(a0, f, vz);
        const v4f z1 = MFMA16(a1, f, vz);
        u2i u0; u0.x = z0p[li][0][0]; u0.y = z0p[li][0][1];
        u2i u1; u1.x = z0p[li][1][0]; u1.y = z0p[li][1][1];
        fin[li][0] = z0 + ub4(u0);
        fin[li][1] = z1 + ub4(u1);
    }
    #pragma unroll
    for (int mt = 0; mt < 2; ++mt)
    #pragma unroll
    for (int rg = 0; rg < 4; ++rg) {
        const int p0 = 4 * w + 32 * (mt * 16 + lk * 4 + rg);
        v4f vv;
        vv.x = fin[0][mt][rg]; vv.y = fin[1][mt][rg];
        vv.z = fin[2][mt][rg]; vv.w = fin[3][mt][rg];
        *(v4f*)(lds + (lr << 12) + ((p0 << 2) ^ ((lr & 7) << 4))) = vv;
    }
    BAR();
    // seg6: coalesced out = staged + b2
    {
        const int row = t >> 5, c0 = (t & 31) * 4;
        #pragma unroll
        for (int i = 0; i < 8; ++i) {
            const int col = c0 + 128 * i;
            v4f ov = *(const v4f*)(lds + (row << 12) + ((col << 2) ^ ((row & 7) << 4)));
            ov += *(const v4f*)(b2 + col);
            *(v4f*)(out + (size_t)(row0 + row) * 1024 + col) = ov;
        }
    }
}

extern "C" void kernel_launch(void* const* d_in, const int* in_sizes, int n_in,
                              void* d_out, int out_size, void* d_ws, size_t ws_size,
                              hipStream_t stream) {
    const float* x   = (const float*)d_in[0];
    const float* tw1 = (const float*)d_in[1];
    const float* b1  = (const float*)d_in[2];
    const float* tw2 = (const float*)d_in[3];
    const float* b2  = (const float*)d_in[4];

    build_mats<<<192, 64, 0, stream>>>(tw1, tw2, (unsigned short*)d_ws);

    (void)hipFuncSetAttribute((const void*)glu_bfly,
                              hipFuncAttributeMaxDynamicSharedMemorySize, 139264);
    glu_bfly<<<1024, 512, 139264, stream>>>(x, b1, b2, (const bf8*)d_ws,
                                            (float*)d_out);
}